// Round 16
// baseline (147.002 us; speedup 1.0000x reference)
//
#include <hip/hip_runtime.h>
#include <math.h>

constexpr int B_ = 64;
constexpr int N_ = 1000;
constexpr int D_ = 128;
constexpr int E_ = 20000;
constexpr int BN_TOT = B_ * N_;
constexpr float BN_EPS = 1e-5f;
constexpr float NEG_SLOPE = 0.2f;

typedef __attribute__((ext_vector_type(8))) __bf16 bf16x8;
typedef __attribute__((ext_vector_type(4))) float f32x4;
typedef __attribute__((ext_vector_type(2))) float f32x2;
typedef __attribute__((ext_vector_type(4))) unsigned int u32x4;

__device__ __forceinline__ float leaky(float a) { return a >= 0.f ? a : NEG_SLOPE * a; }

__device__ __forceinline__ bf16x8 cvt8(const float* v) {
    bf16x8 h;
#pragma unroll
    for (int j = 0; j < 8; ++j) h[j] = (__bf16)v[j];
    return h;
}

__device__ __forceinline__ unsigned int pack2(float a, float b) {
    __bf16 b0 = (__bf16)a, b1 = (__bf16)b;
    unsigned int u0 = *(const unsigned short*)&b0;
    unsigned int u1 = *(const unsigned short*)&b1;
    return u0 | (u1 << 16);
}

__device__ __forceinline__ unsigned int packpair(float v, int l) {
    float vp = __shfl_xor(v, 1);
    return pack2(v, vp);   // valid on even lanes: (col, col+1) row-major bf16
}

__device__ __forceinline__ void acc8(u32x4 u, float wg,
                                     f32x2& a0, f32x2& a1, f32x2& a2, f32x2& a3) {
    f32x2 v;
    v.x = __uint_as_float(u.x << 16); v.y = __uint_as_float(u.x & 0xffff0000u);
    a0 += wg * v;
    v.x = __uint_as_float(u.y << 16); v.y = __uint_as_float(u.y & 0xffff0000u);
    a1 += wg * v;
    v.x = __uint_as_float(u.z << 16); v.y = __uint_as_float(u.z & 0xffff0000u);
    a2 += wg * v;
    v.x = __uint_as_float(u.w << 16); v.y = __uint_as_float(u.w & 0xffff0000u);
    a3 += wg * v;
}

// ---------------- merged prep: wprep | gvec | emb_scores ----------------
__global__ __launch_bounds__(256) void k_prep(const float* __restrict__ lin_w,
                                              const float* __restrict__ v_w,
                                              const float* __restrict__ f_w1,
                                              const float* __restrict__ emb,
                                              const float* __restrict__ att_em_i,
                                              const float* __restrict__ att_em_j,
                                              const float* __restrict__ f_w2,
                                              const float* __restrict__ f_b2,
                                              const float* __restrict__ out_w,
                                              const float* __restrict__ out_b,
                                              __bf16* __restrict__ wcat_h, __bf16* __restrict__ wcat_l,
                                              __bf16* __restrict__ f1_h, __bf16* __restrict__ f1_l,
                                              float* __restrict__ eemi, float* __restrict__ eemj,
                                              float* __restrict__ g, float* __restrict__ c0) {
    const int blk = blockIdx.x;
    const int tid = threadIdx.x;
    if (blk < 256) {            // weight split bf16 hi/lo
        int i = blk * 256 + tid;
        if (i < 32768) {
            float v = (i < 16384) ? lin_w[i] : v_w[i - 16384];
            __bf16 h = (__bf16)v;
            wcat_h[i] = h;
            wcat_l[i] = (__bf16)(v - (float)h);
        } else {
            int j = i - 32768;
            float v = f_w1[j];
            __bf16 h = (__bf16)v;
            f1_h[j] = h;
            f1_l[j] = (__bf16)(v - (float)h);
        }
    } else if (blk == 256) {    // g vector + c0
        if (tid < 128) {
            float s = 0.f;
            for (int k = 0; k < D_; ++k) s += out_w[k] * f_w2[k * D_ + tid];
            g[tid] = s;
            if (tid == 0) {
                float c = out_b[0];
                for (int k = 0; k < D_; ++k) c += out_w[k] * f_b2[k];
                *c0 = c;
            }
        }
    } else {                    // emb scores: blocks 257..506, 4 nodes each
        const int wid = tid >> 6;
        const int lane = tid & 63;
        const int n = (blk - 257) * 4 + wid;
        const float* er = emb + (size_t)n * D_;
        float e0 = er[lane], e1 = er[lane + 64];
        float si = e0 * att_em_i[lane] + e1 * att_em_i[lane + 64];
        float sj = e0 * att_em_j[lane] + e1 * att_em_j[lane + 64];
        for (int off = 32; off > 0; off >>= 1) {
            si += __shfl_down(si, off);
            sj += __shfl_down(sj, off);
        }
        if (lane == 0) { eemi[n] = si; eemj[n] = sj; }
    }
}

// ---------------- CSR build: single block, LDS histogram + scan + scatter ----------------
__global__ __launch_bounds__(1024) void k_csr(const int* __restrict__ ei,
                                              int* __restrict__ offs,
                                              int* __restrict__ csr_src) {
    __shared__ int hist[N_ + 1];
    __shared__ int cur[N_];
    const int tid = threadIdx.x;
    for (int i = tid; i <= N_; i += 1024) hist[i] = 0;
    __syncthreads();
    for (int e = tid; e < E_; e += 1024) atomicAdd(&hist[ei[E_ + e] + 1], 1);
    __syncthreads();
    for (int off = 1; off <= N_; off <<= 1) {
        int v = 0;
        if (tid <= N_) { v = hist[tid]; if (tid >= off) v += hist[tid - off]; }
        __syncthreads();
        if (tid <= N_) hist[tid] = v;
        __syncthreads();
    }
    if (tid <= N_) offs[tid] = hist[tid];
    for (int i = tid; i < N_; i += 1024) cur[i] = 0;
    __syncthreads();
    for (int e = tid; e < E_; e += 1024) {
        int dn = ei[E_ + e];
        int pos = hist[dn] + atomicAdd(&cur[dn], 1);
        csr_src[pos] = ei[e];
    }
}

// ---------------- MFMA dual GEMM + fused scores, bf16-only outputs ----------------
__global__ __launch_bounds__(512) void k_mfma_dual(const float* __restrict__ data,
                                                   const __bf16* __restrict__ wcat_h,
                                                   const __bf16* __restrict__ wcat_l,
                                                   const float* __restrict__ v_b,
                                                   const float* __restrict__ att_i,
                                                   const float* __restrict__ att_j,
                                                   const float* __restrict__ eemi,
                                                   const float* __restrict__ eemj,
                                                   float* __restrict__ ni,
                                                   float* __restrict__ nj,
                                                   unsigned int* __restrict__ xb,
                                                   unsigned int* __restrict__ tb) {
    const int tid = threadIdx.x;
    const int w = tid >> 6;
    const int l = tid & 63;
    bf16x8 Bh[2][4], Bl[2][4];
#pragma unroll
    for (int nt = 0; nt < 2; ++nt) {
        const int n = w * 32 + nt * 16 + (l & 15);
#pragma unroll
        for (int kk = 0; kk < 4; ++kk) {
            const int k = kk * 32 + (l >> 4) * 8;
            Bh[nt][kk] = *(const bf16x8*)&wcat_h[n * D_ + k];
            Bl[nt][kk] = *(const bf16x8*)&wcat_l[n * D_ + k];
        }
    }
    float vb[2] = {0.f, 0.f};
    float ai[2] = {0.f, 0.f}, aj[2] = {0.f, 0.f};
    if (w >= 4) {
#pragma unroll
        for (int nt = 0; nt < 2; ++nt) vb[nt] = v_b[w * 32 + nt * 16 + (l & 15) - 128];
    } else {
#pragma unroll
        for (int nt = 0; nt < 2; ++nt) {
            const int col = w * 32 + nt * 16 + (l & 15);
            ai[nt] = att_i[col];
            aj[nt] = att_j[col];
        }
    }
    __shared__ __align__(16) __bf16 dh[2][32 * D_];
    __shared__ float sred_i[4][32];
    __shared__ float sred_j[4][32];
    const int srow = tid >> 4;
    const int skq = (tid & 15) * 8;
    const int soff = srow * D_ + (skq ^ ((srow & 7) * 8));
    const int nchunks = BN_TOT / 32;
    float4 q0, q1;
    {
        const float* src = data + (size_t)(blockIdx.x * 32 + srow) * D_ + skq;
        q0 = *(const float4*)src;
        q1 = *(const float4*)(src + 4);
        float v[8] = {q0.x, q0.y, q0.z, q0.w, q1.x, q1.y, q1.z, q1.w};
        *(bf16x8*)&dh[0][soff] = cvt8(v);
    }
    int cur = 0;
    for (int ch = blockIdx.x; ch < nchunks; ch += gridDim.x) {
        const int nxt = ch + gridDim.x;
        if (nxt < nchunks) {
            const float* src = data + (size_t)(nxt * 32 + srow) * D_ + skq;
            q0 = *(const float4*)src;
            q1 = *(const float4*)(src + 4);
        }
        __syncthreads();
        f32x4 acc[2][2];
#pragma unroll
        for (int mt = 0; mt < 2; ++mt)
#pragma unroll
            for (int nt = 0; nt < 2; ++nt) acc[mt][nt] = (f32x4){0.f, 0.f, 0.f, 0.f};
#pragma unroll
        for (int mt = 0; mt < 2; ++mt) {
#pragma unroll
            for (int kk = 0; kk < 4; ++kk) {
                const int aidx = (mt * 16 + (l & 15)) * D_ + ((kk * 32 + (l >> 4) * 8) ^ ((l & 7) * 8));
                bf16x8 ah = *(const bf16x8*)&dh[cur][aidx];
#pragma unroll
                for (int nt = 0; nt < 2; ++nt) {
                    acc[mt][nt] = __builtin_amdgcn_mfma_f32_16x16x32_bf16(ah, Bh[nt][kk], acc[mt][nt], 0, 0, 0);
                    acc[mt][nt] = __builtin_amdgcn_mfma_f32_16x16x32_bf16(ah, Bl[nt][kk], acc[mt][nt], 0, 0, 0);
                }
            }
        }
        const int row0 = ch * 32;
        if (w < 4) {
            float pi[8], pj[8];
#pragma unroll
            for (int k2 = 0; k2 < 8; ++k2) { pi[k2] = 0.f; pj[k2] = 0.f; }
#pragma unroll
            for (int mt = 0; mt < 2; ++mt) {
#pragma unroll
                for (int nt = 0; nt < 2; ++nt) {
                    const int col = w * 32 + nt * 16 + (l & 15);
#pragma unroll
                    for (int r = 0; r < 4; ++r) {
                        float v = acc[mt][nt][r];
                        pi[mt * 4 + r] += v * ai[nt];
                        pj[mt * 4 + r] += v * aj[nt];
                        unsigned int u = packpair(v, l);
                        if (!(l & 1)) {
                            const int row = row0 + mt * 16 + (l >> 4) * 4 + r;
                            xb[(size_t)row * 64 + (col >> 1)] = u;
                        }
                    }
                }
            }
#pragma unroll
            for (int off = 1; off < 16; off <<= 1) {
#pragma unroll
                for (int k2 = 0; k2 < 8; ++k2) {
                    pi[k2] += __shfl_xor(pi[k2], off);
                    pj[k2] += __shfl_xor(pj[k2], off);
                }
            }
            if ((l & 15) == 0) {
#pragma unroll
                for (int mt = 0; mt < 2; ++mt)
#pragma unroll
                    for (int r = 0; r < 4; ++r) {
                        sred_i[w][mt * 16 + (l >> 4) * 4 + r] = pi[mt * 4 + r];
                        sred_j[w][mt * 16 + (l >> 4) * 4 + r] = pj[mt * 4 + r];
                    }
            }
        } else {
#pragma unroll
            for (int mt = 0; mt < 2; ++mt) {
#pragma unroll
                for (int nt = 0; nt < 2; ++nt) {
                    const int c2 = w * 32 + nt * 16 + (l & 15) - 128;
#pragma unroll
                    for (int r = 0; r < 4; ++r) {
                        float v = acc[mt][nt][r] + vb[nt];
                        unsigned int u = packpair(v, l);
                        if (!(l & 1)) {
                            const int row = row0 + mt * 16 + (l >> 4) * 4 + r;
                            tb[(size_t)row * 64 + (c2 >> 1)] = u;
                        }
                    }
                }
            }
        }
        __syncthreads();
        if (tid < 32) {
            const int row = row0 + tid;
            float si = sred_i[0][tid] + sred_i[1][tid] + sred_i[2][tid] + sred_i[3][tid];
            float sj = sred_j[0][tid] + sred_j[1][tid] + sred_j[2][tid] + sred_j[3][tid];
            const int n = row % N_;
            ni[row] = si + eemi[n];
            nj[row] = sj + eemj[n];
        }
        if (nxt < nchunks) {
            float v[8] = {q0.x, q0.y, q0.z, q0.w, q1.x, q1.y, q1.z, q1.w};
            *(bf16x8*)&dh[cur ^ 1][soff] = cvt8(v);
        }
        cur ^= 1;
    }
}

// ---------------- fused edge softmax + SpMM + BN block-partials ----------------
// Phase 1 (lanes=edges): leaky/max/exp/denominator into LDS (wave-private, no barrier).
// Phase 2 (quarter-wave per edge, u32x4 = 8 channels/lane): packed-f32 FMA gather.
// Epilogue: agg stored packed bf16 (ab); per-block BN partials (non-atomic).
__global__ __launch_bounds__(256) void k_sagg(const unsigned int* __restrict__ xb,
                                              const int* __restrict__ offs,
                                              const int* __restrict__ csr_src,
                                              const float* __restrict__ ni,
                                              const float* __restrict__ nj,
                                              const float* __restrict__ gnn_bias,
                                              unsigned int* __restrict__ ab,
                                              float* __restrict__ partials) {
    constexpr int CAP = 128;
    __shared__ int s_lds[4][CAP];
    __shared__ float w_lds[4][CAP];
    __shared__ f32x4 bns[4][32];
    __shared__ f32x4 bnq[4][32];
    const int swz = (blockIdx.x & 7) * 2000 + (blockIdx.x >> 3);
    const int w = threadIdx.x >> 6;
    const int l = threadIdx.x & 63;
    const int bid = swz * 4 + w;
    const int b = bid / N_;
    const int i = bid - b * N_;
    const int base = b * N_;
    const int e0 = offs[i];
    const int deg = offs[i + 1] - e0;
    const int stg = deg < CAP ? deg : CAP;
    const float nii = ni[bid];
    const float aself = leaky(nii + nj[bid]);
    // ---- phase 1: lanes over edges (wave-private LDS; per-wave DS ordering suffices)
    float aa0 = -1e30f, aa1 = -1e30f;
    if (l < stg) {
        int s = csr_src[e0 + l];
        s_lds[w][l] = s;
        aa0 = leaky(nii + nj[base + s]);
    }
    if (l + 64 < stg) {
        int s = csr_src[e0 + l + 64];
        s_lds[w][l + 64] = s;
        aa1 = leaky(nii + nj[base + s]);
    }
    float amax = fmaxf(aself, fmaxf(aa0, aa1));
    for (int e = e0 + CAP + l; e < e0 + deg; e += 64)
        amax = fmaxf(amax, leaky(nii + nj[base + csr_src[e]]));
    for (int off = 32; off > 0; off >>= 1) amax = fmaxf(amax, __shfl_xor(amax, off));
    const float se = __expf(aself - amax);
    float sum = 0.f;
    if (l < stg) { float ex = __expf(aa0 - amax); w_lds[w][l] = ex; sum += ex; }
    if (l + 64 < stg) { float ex = __expf(aa1 - amax); w_lds[w][l + 64] = ex; sum += ex; }
    for (int off = 32; off > 0; off >>= 1) sum += __shfl_xor(sum, off);
    float denom = se + sum;
    // ---- phase 2: quarter-wave per edge, u32x4 = 8 channels/lane
    const int qw = l >> 4;     // edge slot 0..3
    const int c = l & 15;      // u32x4 index: channels 8c..8c+7
    const u32x4* x4 = (const u32x4*)xb;
    f32x2 a0 = (f32x2){0.f, 0.f}, a1 = (f32x2){0.f, 0.f};
    f32x2 a2 = (f32x2){0.f, 0.f}, a3 = (f32x2){0.f, 0.f};
    if (qw == 0) {   // self term
        u32x4 u = x4[(size_t)bid * 16 + c];
        acc8(u, se, a0, a1, a2, a3);
    }
    int k = 0;
    for (; k + 8 <= stg; k += 8) {   // 2 edges per quarter-wave in flight
        int e1_ = k + qw, e2_ = k + 4 + qw;
        int s1 = s_lds[w][e1_], s2 = s_lds[w][e2_];
        float wg1 = w_lds[w][e1_], wg2 = w_lds[w][e2_];
        u32x4 u1 = x4[(size_t)(base + s1) * 16 + c];
        u32x4 u2 = x4[(size_t)(base + s2) * 16 + c];
        acc8(u1, wg1, a0, a1, a2, a3);
        acc8(u2, wg2, a0, a1, a2, a3);
    }
    for (; k + 4 <= stg; k += 4) {
        int e = k + qw;
        int s = s_lds[w][e];
        float wg = w_lds[w][e];
        u32x4 u = x4[(size_t)(base + s) * 16 + c];
        acc8(u, wg, a0, a1, a2, a3);
    }
    if (k + qw < stg) {              // tail 0..3 edges
        int e = k + qw;
        int s = s_lds[w][e];
        float wg = w_lds[w][e];
        u32x4 u = x4[(size_t)(base + s) * 16 + c];
        acc8(u, wg, a0, a1, a2, a3);
    }
    for (int e = e0 + CAP; e < e0 + deg; ++e) {   // overflow fallback (~never)
        int s = csr_src[e];
        float wg = __expf(leaky(nii + nj[base + s]) - amax);
        if (qw == 0) {
            u32x4 u = x4[(size_t)(base + s) * 16 + c];
            acc8(u, wg, a0, a1, a2, a3);
        }
        denom += wg;
    }
    // combine quarter-waves (lanes l, l^16, l^32, l^48)
#pragma unroll
    for (int off = 16; off <= 32; off <<= 1) {
        a0.x += __shfl_xor(a0.x, off); a0.y += __shfl_xor(a0.y, off);
        a1.x += __shfl_xor(a1.x, off); a1.y += __shfl_xor(a1.y, off);
        a2.x += __shfl_xor(a2.x, off); a2.y += __shfl_xor(a2.y, off);
        a3.x += __shfl_xor(a3.x, off); a3.y += __shfl_xor(a3.y, off);
    }
    if (qw == 0) {
        const float dn = 1.f / denom;
        const f32x4* gb4 = (const f32x4*)gnn_bias;
        f32x4 o0, o1;
        f32x4 g0 = gb4[2 * c], g1 = gb4[2 * c + 1];
        o0.x = a0.x * dn + g0.x; o0.y = a0.y * dn + g0.y;
        o0.z = a1.x * dn + g0.z; o0.w = a1.y * dn + g0.w;
        o1.x = a2.x * dn + g1.x; o1.y = a2.y * dn + g1.y;
        o1.z = a3.x * dn + g1.z; o1.w = a3.y * dn + g1.w;
        u32x4 up;
        up.x = pack2(o0.x, o0.y); up.y = pack2(o0.z, o0.w);
        up.z = pack2(o1.x, o1.y); up.w = pack2(o1.z, o1.w);
        __builtin_nontemporal_store(up, (u32x4*)ab + (size_t)bid * 16 + c);
        bns[w][2 * c] = o0;  bns[w][2 * c + 1] = o1;
        bnq[w][2 * c] = o0 * o0;  bnq[w][2 * c + 1] = o1 * o1;
    }
    __syncthreads();
    if (threadIdx.x < 32) {        // per-block partials, non-atomic
        const int cc = threadIdx.x;
        f32x4 s = bns[0][cc] + bns[1][cc] + bns[2][cc] + bns[3][cc];
        f32x4 q = bnq[0][cc] + bnq[1][cc] + bnq[2][cc] + bnq[3][cc];
        f32x4* p = (f32x4*)partials + (size_t)blockIdx.x * 64;
        p[cc] = s;
        p[32 + cc] = q;
    }
}

// ---------------- BN reduce: 16000 partial rows -> 128 -> scale/shift ----------------
__global__ __launch_bounds__(256) void k_bn_redA(const float* __restrict__ partials,
                                                 float* __restrict__ partial2) {
    const int t = threadIdx.x;
    float s = 0.f;
    const int r0 = blockIdx.x * 125;
    for (int r = r0; r < r0 + 125; ++r)
        s += partials[(size_t)r * 256 + t];
    partial2[(size_t)blockIdx.x * 256 + t] = s;
}

__global__ __launch_bounds__(256) void k_bn_finB(const float* __restrict__ partial2,
                                                 const float* __restrict__ gamma,
                                                 const float* __restrict__ beta,
                                                 float* __restrict__ scale,
                                                 float* __restrict__ shift) {
    const int t = threadIdx.x;
    float s = 0.f;
    for (int r = 0; r < 128; ++r) s += partial2[(size_t)r * 256 + t];
    __shared__ float tot[256];
    tot[t] = s;
    __syncthreads();
    if (t < 128) {
        float mu = tot[t] * (1.f / BN_TOT);
        float var = tot[128 + t] * (1.f / BN_TOT) - mu * mu;
        float sc = gamma[t] * rsqrtf(var + BN_EPS);
        scale[t] = sc;
        shift[t] = beta[t] - mu * sc;
    }
}

// ---------------- MFMA fusion, double-buffered; both halves read as packed bf16 ----------
__global__ __launch_bounds__(512) void k_mfma_fusion(const unsigned int* __restrict__ ab,
                                                     const unsigned int* __restrict__ tb,
                                                     const __bf16* __restrict__ f1_h,
                                                     const __bf16* __restrict__ f1_l,
                                                     const float* __restrict__ f_b1,
                                                     const float* __restrict__ scale,
                                                     const float* __restrict__ shift,
                                                     const float* __restrict__ g,
                                                     const float* __restrict__ c0p,
                                                     float* __restrict__ out) {
    const int tid = threadIdx.x;
    const int w = tid >> 6;
    const int l = tid & 63;
    const float c0v = *c0p;
    bf16x8 Fh[8], Fl[8];
    const int ncol = w * 16 + (l & 15);
#pragma unroll
    for (int kk = 0; kk < 8; ++kk) {
        const int k = kk * 32 + (l >> 4) * 8;
        Fh[kk] = *(const bf16x8*)&f1_h[ncol * 256 + k];
        Fl[kk] = *(const bf16x8*)&f1_l[ncol * 256 + k];
    }
    const float b1c = f_b1[ncol];
    const float gc = g[ncol];
    __shared__ __align__(16) __bf16 ch_[2][32 * 256];
    __shared__ float part[8][32];
    const int srow = tid >> 4;
    const int scb = (tid & 15) * 16;
    const bool isagg = scb < 128;
    float4 sc4[4], sh4[4];
    if (isagg) {
#pragma unroll
        for (int q = 0; q < 4; ++q) {
            sc4[q] = *(const float4*)&scale[scb + q * 4];
            sh4[q] = *(const float4*)&shift[scb + q * 4];
        }
    }
    const unsigned int* basep = isagg ? ab : tb;
    const int uoff = (scb & 127) >> 1;
    const int nchunks = BN_TOT / 32;
    u32x4 qu[2];
    auto loadc = [&](int chk) {
        const unsigned int* srcp = basep + (size_t)(chk * 32 + srow) * 64 + uoff;
        qu[0] = *(const u32x4*)srcp;
        qu[1] = *(const u32x4*)(srcp + 4);
    };
    auto storec = [&](int buf) {
        if (isagg) {
            float v[16];
            unsigned int us[8] = {qu[0].x, qu[0].y, qu[0].z, qu[0].w,
                                  qu[1].x, qu[1].y, qu[1].z, qu[1].w};
#pragma unroll
            for (int j = 0; j < 8; ++j) {
                v[j * 2 + 0] = __uint_as_float(us[j] << 16);
                v[j * 2 + 1] = __uint_as_float(us[j] & 0xffff0000u);
            }
#pragma unroll
            for (int qq = 0; qq < 4; ++qq) {
                v[qq * 4 + 0] = fmaxf(v[qq * 4 + 0] * sc4[qq].x + sh4[qq].x, 0.f);
                v[qq * 4 + 1] = fmaxf(v[qq * 4 + 1] * sc4[qq].y + sh4[qq].y, 0.f);
                v[qq * 4 + 2] = fmaxf(v[qq * 4 + 2] * sc4[qq].z + sh4[qq].z, 0.f);
                v[qq * 4 + 3] = fmaxf(v[qq * 4 + 3] * sc4[qq].w + sh4[qq].w, 0.f);
            }
#pragma unroll
            for (int hh = 0; hh < 2; ++hh) {
                const int c = scb + hh * 8;
                const int idx = srow * 256 + (c ^ ((srow & 7) * 8));
                *(bf16x8*)&ch_[buf][idx] = cvt8(v + hh * 8);
            }
        } else {
#pragma unroll
            for (int hh = 0; hh < 2; ++hh) {
                const int c = scb + hh * 8;
                const int idx = srow * 256 + (c ^ ((srow & 7) * 8));
                *(bf16x8*)&ch_[buf][idx] = *(const bf16x8*)&qu[hh];
            }
        }
    };
    loadc(blockIdx.x);
    storec(0);
    int cur = 0;
    for (int chk = blockIdx.x; chk < nchunks; chk += gridDim.x) {
        const int nxt = chk + gridDim.x;
        if (nxt < nchunks) loadc(nxt);
        __syncthreads();                 // (A) buf[cur] visible; part free
#pragma unroll
        for (int mt = 0; mt < 2; ++mt) {
            f32x4 acc = (f32x4){0.f, 0.f, 0.f, 0.f};
#pragma unroll
            for (int kk = 0; kk < 8; ++kk) {
                const int ai = (mt * 16 + (l & 15)) * 256 + ((kk * 32 + (l >> 4) * 8) ^ ((l & 7) * 8));
                bf16x8 ah = *(const bf16x8*)&ch_[cur][ai];
                acc = __builtin_amdgcn_mfma_f32_16x16x32_bf16(ah, Fh[kk], acc, 0, 0, 0);
                acc = __builtin_amdgcn_mfma_f32_16x16x32_bf16(ah, Fl[kk], acc, 0, 0, 0);
            }
            float p[4];
#pragma unroll
            for (int r = 0; r < 4; ++r) p[r] = fmaxf(acc[r] + b1c, 0.f) * gc;
#pragma unroll
            for (int r = 0; r < 4; ++r) {
                p[r] += __shfl_xor(p[r], 1);
                p[r] += __shfl_xor(p[r], 2);
                p[r] += __shfl_xor(p[r], 4);
                p[r] += __shfl_xor(p[r], 8);
            }
            if ((l & 15) == 0) {
#pragma unroll
                for (int r = 0; r < 4; ++r) part[w][mt * 16 + (l >> 4) * 4 + r] = p[r];
            }
        }
        __syncthreads();                 // (B) part ready; buf[cur] reads done
        if (tid < 32) {
            float s = c0v;
#pragma unroll
            for (int ww = 0; ww < 8; ++ww) s += part[ww][tid];
            out[chk * 32 + tid] = s;
        }
        if (nxt < nchunks) storec(cur ^ 1);
        cur ^= 1;
    }
}

// ---------------- launch ----------------
extern "C" void kernel_launch(void* const* d_in, const int* in_sizes, int n_in,
                              void* d_out, int out_size, void* d_ws, size_t ws_size,
                              hipStream_t stream) {
    const float* data     = (const float*)d_in[0];
    const int*   ei       = (const int*)d_in[1];
    const float* emb      = (const float*)d_in[2];
    const float* lin_w    = (const float*)d_in[3];
    const float* att_i    = (const float*)d_in[4];
    const float* att_j    = (const float*)d_in[5];
    const float* att_em_i = (const float*)d_in[6];
    const float* att_em_j = (const float*)d_in[7];
    const float* gnn_bias = (const float*)d_in[8];
    const float* bn_gamma = (const float*)d_in[9];
    const float* bn_beta  = (const float*)d_in[10];
    // q_w,q_b,k_w,k_b,temperature dead (W=1 -> softmax over single element -> attn==1)
    const float* v_w      = (const float*)d_in[15];
    const float* v_b      = (const float*)d_in[16];
    const float* f_w1     = (const float*)d_in[18];
    const float* f_b1     = (const float*)d_in[19];
    const float* f_w2     = (const float*)d_in[20];
    const float* f_b2     = (const float*)d_in[21];
    const float* out_w    = (const float*)d_in[22];
    const float* out_b    = (const float*)d_in[23];
    float* out = (float*)d_out;

    float* ws = (float*)d_ws;
    float* x      = ws;                                 // BN*D (unused; layout kept)
    float* tmat   = x + (size_t)BN_TOT * D_;            // tb = first BN*64 uints
    float* aggr   = tmat + (size_t)BN_TOT * D_;         // ab = first BN*64 uints
    float* ni     = aggr + (size_t)BN_TOT * D_;         // BN
    float* nj     = ni + BN_TOT;                        // BN
    float* eemi   = nj + BN_TOT;                        // N
    float* eemj   = eemi + N_;                          // N
    float* g      = eemj + N_;                          // D
    float* c0     = g + D_;                             // 1 (pad 8)
    float* scale  = c0 + 8;                             // D
    float* shift  = scale + D_;                         // D
    int* offs     = (int*)(shift + D_);                 // 1024
    int* cursor   = offs + 1024;                        // 1024 (unused)
    float* bn_sum = (float*)(cursor + 1024);            // 128 (unused)
    float* bn_sq  = bn_sum + D_;                        // 128 (unused)
    int* csr_src  = (int*)(bn_sq + D_);                 // E
    float* partials = (float*)(csr_src + E_);           // 16000*256 floats
    float* partial2 = partials + (size_t)16000 * 256;   // 128*256 floats
    __bf16* wcat_h = (__bf16*)(partial2 + 128 * 256);   // 256*128
    __bf16* wcat_l = wcat_h + 256 * 128;                // 256*128
    __bf16* f1_h   = wcat_l + 256 * 128;                // 128*256
    __bf16* f1_l   = f1_h + 128 * 256;                  // 128*256
    unsigned int* xb = (unsigned int*)(f1_l + 128 * 256);  // BN*64 uints
    unsigned int* tb = (unsigned int*)tmat;             // BN*64 uints (packed bf16 t)
    unsigned int* ab = (unsigned int*)aggr;             // BN*64 uints (packed bf16 agg)

    k_prep<<<507, 256, 0, stream>>>(lin_w, v_w, f_w1, emb, att_em_i, att_em_j,
                                    f_w2, f_b2, out_w, out_b,
                                    wcat_h, wcat_l, f1_h, f1_l,
                                    eemi, eemj, g, c0);
    k_csr<<<1, 1024, 0, stream>>>(ei, offs, csr_src);
    k_mfma_dual<<<500, 512, 0, stream>>>(data, wcat_h, wcat_l, v_b,
                                         att_i, att_j, eemi, eemj,
                                         ni, nj, xb, tb);
    k_sagg<<<BN_TOT / 4, 256, 0, stream>>>(xb, offs, csr_src, ni, nj, gnn_bias, ab, partials);
    k_bn_redA<<<128, 256, 0, stream>>>(partials, partial2);
    k_bn_finB<<<1, 256, 0, stream>>>(partial2, bn_gamma, bn_beta, scale, shift);
    k_mfma_fusion<<<500, 512, 0, stream>>>(ab, tb, f1_h, f1_l, f_b1, scale, shift, g, c0, out);
}

// Round 17
// 135.587 us; speedup vs baseline: 1.0842x; 1.0842x over previous
//
#include <hip/hip_runtime.h>
#include <math.h>

constexpr int B_ = 64;
constexpr int N_ = 1000;
constexpr int D_ = 128;
constexpr int E_ = 20000;
constexpr int BN_TOT = B_ * N_;
constexpr float BN_EPS = 1e-5f;
constexpr float NEG_SLOPE = 0.2f;

typedef __attribute__((ext_vector_type(8))) __bf16 bf16x8;
typedef __attribute__((ext_vector_type(4))) float f32x4;
typedef __attribute__((ext_vector_type(2))) float f32x2;
typedef __attribute__((ext_vector_type(2))) unsigned int u32x2;

__device__ __forceinline__ float leaky(float a) { return a >= 0.f ? a : NEG_SLOPE * a; }

__device__ __forceinline__ bf16x8 cvt8(const float* v) {
    bf16x8 h;
#pragma unroll
    for (int j = 0; j < 8; ++j) h[j] = (__bf16)v[j];
    return h;
}

__device__ __forceinline__ unsigned int pack2(float a, float b) {
    __bf16 b0 = (__bf16)a, b1 = (__bf16)b;
    unsigned int u0 = *(const unsigned short*)&b0;
    unsigned int u1 = *(const unsigned short*)&b1;
    return u0 | (u1 << 16);
}

__device__ __forceinline__ unsigned int packpair(float v, int l) {
    float vp = __shfl_xor(v, 1);
    return pack2(v, vp);   // valid on even lanes: (col, col+1) row-major bf16
}

// ---------------- merged prep: wprep | zero | gvec | emb_scores ----------------
__global__ __launch_bounds__(256) void k_prep(const float* __restrict__ lin_w,
                                              const float* __restrict__ v_w,
                                              const float* __restrict__ f_w1,
                                              const float* __restrict__ emb,
                                              const float* __restrict__ att_em_i,
                                              const float* __restrict__ att_em_j,
                                              const float* __restrict__ f_w2,
                                              const float* __restrict__ f_b2,
                                              const float* __restrict__ out_w,
                                              const float* __restrict__ out_b,
                                              __bf16* __restrict__ wcat_h, __bf16* __restrict__ wcat_l,
                                              __bf16* __restrict__ f1_h, __bf16* __restrict__ f1_l,
                                              float* __restrict__ eemi, float* __restrict__ eemj,
                                              float* __restrict__ g, float* __restrict__ c0,
                                              int* __restrict__ zbase) {
    const int blk = blockIdx.x;
    const int tid = threadIdx.x;
    if (blk < 256) {            // weight split bf16 hi/lo
        int i = blk * 256 + tid;
        if (i < 32768) {
            float v = (i < 16384) ? lin_w[i] : v_w[i - 16384];
            __bf16 h = (__bf16)v;
            wcat_h[i] = h;
            wcat_l[i] = (__bf16)(v - (float)h);
        } else {
            int j = i - 32768;
            float v = f_w1[j];
            __bf16 h = (__bf16)v;
            f1_h[j] = h;
            f1_l[j] = (__bf16)(v - (float)h);
        }
    } else if (blk == 256) {    // zero counters (offs + cursor)
        for (int k = tid; k < 2304; k += 256) zbase[k] = 0;
    } else if (blk == 257) {    // g vector + c0
        if (tid < 128) {
            float s = 0.f;
            for (int k = 0; k < D_; ++k) s += out_w[k] * f_w2[k * D_ + tid];
            g[tid] = s;
            if (tid == 0) {
                float c = out_b[0];
                for (int k = 0; k < D_; ++k) c += out_w[k] * f_b2[k];
                *c0 = c;
            }
        }
    } else {                    // emb scores: blocks 258..507, 4 nodes each
        const int wid = tid >> 6;
        const int lane = tid & 63;
        const int n = (blk - 258) * 4 + wid;
        const float* er = emb + (size_t)n * D_;
        float e0 = er[lane], e1 = er[lane + 64];
        float si = e0 * att_em_i[lane] + e1 * att_em_i[lane + 64];
        float sj = e0 * att_em_j[lane] + e1 * att_em_j[lane + 64];
        for (int off = 32; off > 0; off >>= 1) {
            si += __shfl_down(si, off);
            sj += __shfl_down(sj, off);
        }
        if (lane == 0) { eemi[n] = si; eemj[n] = sj; }
    }
}

// ---------------- CSR build ----------------
__global__ void k_count(const int* __restrict__ ei, int* __restrict__ offs) {
    int e = blockIdx.x * blockDim.x + threadIdx.x;
    if (e < E_) atomicAdd(&offs[ei[E_ + e] + 1], 1);
}

__global__ __launch_bounds__(1024) void k_scan(int* __restrict__ offs) {
    __shared__ int s[N_ + 1];
    int tid = threadIdx.x;
    if (tid <= N_) s[tid] = offs[tid];
    __syncthreads();
    for (int off = 1; off <= N_; off <<= 1) {
        int v = 0;
        if (tid <= N_) { v = s[tid]; if (tid >= off) v += s[tid - off]; }
        __syncthreads();
        if (tid <= N_) s[tid] = v;
        __syncthreads();
    }
    if (tid <= N_) offs[tid] = s[tid];
}

__global__ void k_scatter(const int* __restrict__ ei, const int* __restrict__ offs,
                          int* __restrict__ cursor, int* __restrict__ csr_src) {
    int e = blockIdx.x * blockDim.x + threadIdx.x;
    if (e < E_) {
        int dn = ei[E_ + e];
        int pos = offs[dn] + atomicAdd(&cursor[dn], 1);
        csr_src[pos] = ei[e];
    }
}

// ---------------- MFMA dual GEMM + fused scores, bf16-only outputs ----------------
__global__ __launch_bounds__(512) void k_mfma_dual(const float* __restrict__ data,
                                                   const __bf16* __restrict__ wcat_h,
                                                   const __bf16* __restrict__ wcat_l,
                                                   const float* __restrict__ v_b,
                                                   const float* __restrict__ att_i,
                                                   const float* __restrict__ att_j,
                                                   const float* __restrict__ eemi,
                                                   const float* __restrict__ eemj,
                                                   float* __restrict__ ni,
                                                   float* __restrict__ nj,
                                                   unsigned int* __restrict__ xb,
                                                   unsigned int* __restrict__ tb) {
    const int tid = threadIdx.x;
    const int w = tid >> 6;
    const int l = tid & 63;
    bf16x8 Bh[2][4], Bl[2][4];
#pragma unroll
    for (int nt = 0; nt < 2; ++nt) {
        const int n = w * 32 + nt * 16 + (l & 15);
#pragma unroll
        for (int kk = 0; kk < 4; ++kk) {
            const int k = kk * 32 + (l >> 4) * 8;
            Bh[nt][kk] = *(const bf16x8*)&wcat_h[n * D_ + k];
            Bl[nt][kk] = *(const bf16x8*)&wcat_l[n * D_ + k];
        }
    }
    float vb[2] = {0.f, 0.f};
    float ai[2] = {0.f, 0.f}, aj[2] = {0.f, 0.f};
    if (w >= 4) {
#pragma unroll
        for (int nt = 0; nt < 2; ++nt) vb[nt] = v_b[w * 32 + nt * 16 + (l & 15) - 128];
    } else {
#pragma unroll
        for (int nt = 0; nt < 2; ++nt) {
            const int col = w * 32 + nt * 16 + (l & 15);
            ai[nt] = att_i[col];
            aj[nt] = att_j[col];
        }
    }
    __shared__ __align__(16) __bf16 dh[2][32 * D_];
    __shared__ float sred_i[4][32];
    __shared__ float sred_j[4][32];
    const int srow = tid >> 4;
    const int skq = (tid & 15) * 8;
    const int soff = srow * D_ + (skq ^ ((srow & 7) * 8));
    const int nchunks = BN_TOT / 32;
    float4 q0, q1;
    {
        const float* src = data + (size_t)(blockIdx.x * 32 + srow) * D_ + skq;
        q0 = *(const float4*)src;
        q1 = *(const float4*)(src + 4);
        float v[8] = {q0.x, q0.y, q0.z, q0.w, q1.x, q1.y, q1.z, q1.w};
        *(bf16x8*)&dh[0][soff] = cvt8(v);
    }
    int cur = 0;
    for (int ch = blockIdx.x; ch < nchunks; ch += gridDim.x) {
        const int nxt = ch + gridDim.x;
        if (nxt < nchunks) {
            const float* src = data + (size_t)(nxt * 32 + srow) * D_ + skq;
            q0 = *(const float4*)src;
            q1 = *(const float4*)(src + 4);
        }
        __syncthreads();
        f32x4 acc[2][2];
#pragma unroll
        for (int mt = 0; mt < 2; ++mt)
#pragma unroll
            for (int nt = 0; nt < 2; ++nt) acc[mt][nt] = (f32x4){0.f, 0.f, 0.f, 0.f};
#pragma unroll
        for (int mt = 0; mt < 2; ++mt) {
#pragma unroll
            for (int kk = 0; kk < 4; ++kk) {
                const int aidx = (mt * 16 + (l & 15)) * D_ + ((kk * 32 + (l >> 4) * 8) ^ ((l & 7) * 8));
                bf16x8 ah = *(const bf16x8*)&dh[cur][aidx];
#pragma unroll
                for (int nt = 0; nt < 2; ++nt) {
                    acc[mt][nt] = __builtin_amdgcn_mfma_f32_16x16x32_bf16(ah, Bh[nt][kk], acc[mt][nt], 0, 0, 0);
                    acc[mt][nt] = __builtin_amdgcn_mfma_f32_16x16x32_bf16(ah, Bl[nt][kk], acc[mt][nt], 0, 0, 0);
                }
            }
        }
        const int row0 = ch * 32;
        if (w < 4) {
            float pi[8], pj[8];
#pragma unroll
            for (int k2 = 0; k2 < 8; ++k2) { pi[k2] = 0.f; pj[k2] = 0.f; }
#pragma unroll
            for (int mt = 0; mt < 2; ++mt) {
#pragma unroll
                for (int nt = 0; nt < 2; ++nt) {
                    const int col = w * 32 + nt * 16 + (l & 15);
#pragma unroll
                    for (int r = 0; r < 4; ++r) {
                        float v = acc[mt][nt][r];
                        pi[mt * 4 + r] += v * ai[nt];
                        pj[mt * 4 + r] += v * aj[nt];
                        unsigned int u = packpair(v, l);
                        if (!(l & 1)) {
                            const int row = row0 + mt * 16 + (l >> 4) * 4 + r;
                            xb[(size_t)row * 64 + (col >> 1)] = u;
                        }
                    }
                }
            }
#pragma unroll
            for (int off = 1; off < 16; off <<= 1) {
#pragma unroll
                for (int k2 = 0; k2 < 8; ++k2) {
                    pi[k2] += __shfl_xor(pi[k2], off);
                    pj[k2] += __shfl_xor(pj[k2], off);
                }
            }
            if ((l & 15) == 0) {
#pragma unroll
                for (int mt = 0; mt < 2; ++mt)
#pragma unroll
                    for (int r = 0; r < 4; ++r) {
                        sred_i[w][mt * 16 + (l >> 4) * 4 + r] = pi[mt * 4 + r];
                        sred_j[w][mt * 16 + (l >> 4) * 4 + r] = pj[mt * 4 + r];
                    }
            }
        } else {
#pragma unroll
            for (int mt = 0; mt < 2; ++mt) {
#pragma unroll
                for (int nt = 0; nt < 2; ++nt) {
                    const int c2 = w * 32 + nt * 16 + (l & 15) - 128;
#pragma unroll
                    for (int r = 0; r < 4; ++r) {
                        float v = acc[mt][nt][r] + vb[nt];
                        unsigned int u = packpair(v, l);
                        if (!(l & 1)) {
                            const int row = row0 + mt * 16 + (l >> 4) * 4 + r;
                            tb[(size_t)row * 64 + (c2 >> 1)] = u;
                        }
                    }
                }
            }
        }
        __syncthreads();
        if (tid < 32) {
            const int row = row0 + tid;
            float si = sred_i[0][tid] + sred_i[1][tid] + sred_i[2][tid] + sred_i[3][tid];
            float sj = sred_j[0][tid] + sred_j[1][tid] + sred_j[2][tid] + sred_j[3][tid];
            const int n = row % N_;
            ni[row] = si + eemi[n];
            nj[row] = sj + eemj[n];
        }
        if (nxt < nchunks) {
            float v[8] = {q0.x, q0.y, q0.z, q0.w, q1.x, q1.y, q1.z, q1.w};
            *(bf16x8*)&dh[cur ^ 1][soff] = cvt8(v);
        }
        cur ^= 1;
    }
}

// ---------------- fused edge softmax + SpMM + BN block-partials ----------------
// Phase 1 (lanes=edges): leaky/max/exp/denominator into LDS.
// Phase 2 (half-wave per edge, uint2 = 4 channels/lane): packed-f32 FMA gather.
// Epilogue: agg stored packed bf16 (ab); per-block BN partials (non-atomic).
__global__ __launch_bounds__(256) void k_sagg(const unsigned int* __restrict__ xb,
                                              const int* __restrict__ offs,
                                              const int* __restrict__ csr_src,
                                              const float* __restrict__ ni,
                                              const float* __restrict__ nj,
                                              const float* __restrict__ gnn_bias,
                                              unsigned int* __restrict__ ab,
                                              float* __restrict__ partials) {
    constexpr int CAP = 128;
    __shared__ int s_lds[4][CAP];
    __shared__ float w_lds[4][CAP];
    __shared__ f32x4 bns[4][32];
    __shared__ f32x4 bnq[4][32];
    const int swz = (blockIdx.x & 7) * 2000 + (blockIdx.x >> 3);
    const int w = threadIdx.x >> 6;
    const int l = threadIdx.x & 63;
    const int bid = swz * 4 + w;
    const int b = bid / N_;
    const int i = bid - b * N_;
    const int base = b * N_;
    const int e0 = offs[i];
    const int deg = offs[i + 1] - e0;
    const int stg = deg < CAP ? deg : CAP;
    const float nii = ni[bid];
    const float aself = leaky(nii + nj[bid]);
    // ---- phase 1
    float aa0 = -1e30f, aa1 = -1e30f;
    if (l < stg) {
        int s = csr_src[e0 + l];
        s_lds[w][l] = s;
        aa0 = leaky(nii + nj[base + s]);
    }
    if (l + 64 < stg) {
        int s = csr_src[e0 + l + 64];
        s_lds[w][l + 64] = s;
        aa1 = leaky(nii + nj[base + s]);
    }
    float amax = fmaxf(aself, fmaxf(aa0, aa1));
    for (int e = e0 + CAP + l; e < e0 + deg; e += 64)
        amax = fmaxf(amax, leaky(nii + nj[base + csr_src[e]]));
    for (int off = 32; off > 0; off >>= 1) amax = fmaxf(amax, __shfl_xor(amax, off));
    const float se = __expf(aself - amax);
    float sum = 0.f;
    if (l < stg) { float ex = __expf(aa0 - amax); w_lds[w][l] = ex; sum += ex; }
    if (l + 64 < stg) { float ex = __expf(aa1 - amax); w_lds[w][l + 64] = ex; sum += ex; }
    for (int off = 32; off > 0; off >>= 1) sum += __shfl_xor(sum, off);
    float denom = se + sum;
    __syncthreads();
    // ---- phase 2: half-wave per edge, 4 channels/lane
    const int hw = l >> 5;
    const int c = l & 31;
    const uint2* x2 = (const uint2*)xb;
    f32x2 a01 = (f32x2){0.f, 0.f}, a23 = (f32x2){0.f, 0.f};
    if (hw == 0) {
        uint2 u = x2[(size_t)bid * 32 + c];
        f32x2 v01, v23;
        v01.x = __uint_as_float(u.x << 16); v01.y = __uint_as_float(u.x & 0xffff0000u);
        v23.x = __uint_as_float(u.y << 16); v23.y = __uint_as_float(u.y & 0xffff0000u);
        a01 += se * v01;
        a23 += se * v23;
    }
    int k = 0;
    for (; k + 8 <= stg; k += 8) {
        uint2 u[4];
        float wg[4];
#pragma unroll
        for (int j = 0; j < 4; ++j) {
            int e = k + j * 2 + hw;
            int s = s_lds[w][e];
            wg[j] = w_lds[w][e];
            u[j] = x2[(size_t)(base + s) * 32 + c];
        }
#pragma unroll
        for (int j = 0; j < 4; ++j) {
            f32x2 v01, v23;
            v01.x = __uint_as_float(u[j].x << 16); v01.y = __uint_as_float(u[j].x & 0xffff0000u);
            v23.x = __uint_as_float(u[j].y << 16); v23.y = __uint_as_float(u[j].y & 0xffff0000u);
            a01 += wg[j] * v01;
            a23 += wg[j] * v23;
        }
    }
    for (; k + 2 <= stg; k += 2) {
        int e = k + hw;
        int s = s_lds[w][e];
        float wg = w_lds[w][e];
        uint2 u = x2[(size_t)(base + s) * 32 + c];
        f32x2 v01, v23;
        v01.x = __uint_as_float(u.x << 16); v01.y = __uint_as_float(u.x & 0xffff0000u);
        v23.x = __uint_as_float(u.y << 16); v23.y = __uint_as_float(u.y & 0xffff0000u);
        a01 += wg * v01;
        a23 += wg * v23;
    }
    if (k < stg && hw == 0) {
        int s = s_lds[w][k];
        float wg = w_lds[w][k];
        uint2 u = x2[(size_t)(base + s) * 32 + c];
        f32x2 v01, v23;
        v01.x = __uint_as_float(u.x << 16); v01.y = __uint_as_float(u.x & 0xffff0000u);
        v23.x = __uint_as_float(u.y << 16); v23.y = __uint_as_float(u.y & 0xffff0000u);
        a01 += wg * v01;
        a23 += wg * v23;
    }
    for (int e = e0 + CAP; e < e0 + deg; ++e) {   // overflow fallback (~never)
        int s = csr_src[e];
        float wg = __expf(leaky(nii + nj[base + s]) - amax);
        if (hw == 0) {
            uint2 u = x2[(size_t)(base + s) * 32 + c];
            f32x2 v01, v23;
            v01.x = __uint_as_float(u.x << 16); v01.y = __uint_as_float(u.x & 0xffff0000u);
            v23.x = __uint_as_float(u.y << 16); v23.y = __uint_as_float(u.y & 0xffff0000u);
            a01 += wg * v01;
            a23 += wg * v23;
        }
        denom += wg;
    }
    a01.x += __shfl_xor(a01.x, 32);
    a01.y += __shfl_xor(a01.y, 32);
    a23.x += __shfl_xor(a23.x, 32);
    a23.y += __shfl_xor(a23.y, 32);
    if (hw == 0) {
        const float dn = 1.f / denom;
        f32x4 gb = ((const f32x4*)gnn_bias)[c];
        f32x4 o;
        o.x = a01.x * dn + gb.x;
        o.y = a01.y * dn + gb.y;
        o.z = a23.x * dn + gb.z;
        o.w = a23.y * dn + gb.w;
        u32x2 u;
        u.x = pack2(o.x, o.y);
        u.y = pack2(o.z, o.w);
        __builtin_nontemporal_store(u, (u32x2*)ab + (size_t)bid * 32 + c);
        bns[w][c] = o;              // fp32 (pre-rounding) stats
        bnq[w][c] = o * o;
    }
    __syncthreads();
    if (threadIdx.x < 32) {        // per-block partials, non-atomic
        const int cc = threadIdx.x;
        f32x4 s = bns[0][cc] + bns[1][cc] + bns[2][cc] + bns[3][cc];
        f32x4 q = bnq[0][cc] + bnq[1][cc] + bnq[2][cc] + bnq[3][cc];
        f32x4* p = (f32x4*)partials + (size_t)blockIdx.x * 64;
        p[cc] = s;
        p[32 + cc] = q;
    }
}

// ---------------- BN reduce: 16000 partial rows -> 128 -> scale/shift ----------------
__global__ __launch_bounds__(256) void k_bn_redA(const float* __restrict__ partials,
                                                 float* __restrict__ partial2) {
    const int t = threadIdx.x;
    float s = 0.f;
    const int r0 = blockIdx.x * 125;
    for (int r = r0; r < r0 + 125; ++r)
        s += partials[(size_t)r * 256 + t];
    partial2[(size_t)blockIdx.x * 256 + t] = s;
}

__global__ __launch_bounds__(256) void k_bn_finB(const float* __restrict__ partial2,
                                                 const float* __restrict__ gamma,
                                                 const float* __restrict__ beta,
                                                 float* __restrict__ scale,
                                                 float* __restrict__ shift) {
    const int t = threadIdx.x;
    float s = 0.f;
    for (int r = 0; r < 128; ++r) s += partial2[(size_t)r * 256 + t];
    __shared__ float tot[256];
    tot[t] = s;
    __syncthreads();
    if (t < 128) {
        float mu = tot[t] * (1.f / BN_TOT);
        float var = tot[128 + t] * (1.f / BN_TOT) - mu * mu;
        float sc = gamma[t] * rsqrtf(var + BN_EPS);
        scale[t] = sc;
        shift[t] = beta[t] - mu * sc;
    }
}

// ---------------- MFMA fusion, double-buffered; both halves read as packed bf16 ----------
__global__ __launch_bounds__(512) void k_mfma_fusion(const unsigned int* __restrict__ ab,
                                                     const unsigned int* __restrict__ tb,
                                                     const __bf16* __restrict__ f1_h,
                                                     const __bf16* __restrict__ f1_l,
                                                     const float* __restrict__ f_b1,
                                                     const float* __restrict__ scale,
                                                     const float* __restrict__ shift,
                                                     const float* __restrict__ g,
                                                     const float* __restrict__ c0p,
                                                     float* __restrict__ out) {
    const int tid = threadIdx.x;
    const int w = tid >> 6;
    const int l = tid & 63;
    const float c0v = *c0p;
    bf16x8 Fh[8], Fl[8];
    const int ncol = w * 16 + (l & 15);
#pragma unroll
    for (int kk = 0; kk < 8; ++kk) {
        const int k = kk * 32 + (l >> 4) * 8;
        Fh[kk] = *(const bf16x8*)&f1_h[ncol * 256 + k];
        Fl[kk] = *(const bf16x8*)&f1_l[ncol * 256 + k];
    }
    const float b1c = f_b1[ncol];
    const float gc = g[ncol];
    __shared__ __align__(16) __bf16 ch_[2][32 * 256];
    __shared__ float part[8][32];
    const int srow = tid >> 4;
    const int scb = (tid & 15) * 16;
    const bool isagg = scb < 128;
    float4 sc4[4], sh4[4];
    if (isagg) {
#pragma unroll
        for (int q = 0; q < 4; ++q) {
            sc4[q] = *(const float4*)&scale[scb + q * 4];
            sh4[q] = *(const float4*)&shift[scb + q * 4];
        }
    }
    const unsigned int* basep = isagg ? ab : tb;
    const int uoff = (scb & 127) >> 1;
    const int nchunks = BN_TOT / 32;
    uint4 qu[2];
    auto loadc = [&](int chk) {
        const unsigned int* srcp = basep + (size_t)(chk * 32 + srow) * 64 + uoff;
        qu[0] = *(const uint4*)srcp;
        qu[1] = *(const uint4*)(srcp + 4);
    };
    auto storec = [&](int buf) {
        if (isagg) {
            float v[16];
            unsigned int us[8] = {qu[0].x, qu[0].y, qu[0].z, qu[0].w,
                                  qu[1].x, qu[1].y, qu[1].z, qu[1].w};
#pragma unroll
            for (int j = 0; j < 8; ++j) {
                v[j * 2 + 0] = __uint_as_float(us[j] << 16);
                v[j * 2 + 1] = __uint_as_float(us[j] & 0xffff0000u);
            }
#pragma unroll
            for (int qq = 0; qq < 4; ++qq) {
                v[qq * 4 + 0] = fmaxf(v[qq * 4 + 0] * sc4[qq].x + sh4[qq].x, 0.f);
                v[qq * 4 + 1] = fmaxf(v[qq * 4 + 1] * sc4[qq].y + sh4[qq].y, 0.f);
                v[qq * 4 + 2] = fmaxf(v[qq * 4 + 2] * sc4[qq].z + sh4[qq].z, 0.f);
                v[qq * 4 + 3] = fmaxf(v[qq * 4 + 3] * sc4[qq].w + sh4[qq].w, 0.f);
            }
#pragma unroll
            for (int hh = 0; hh < 2; ++hh) {
                const int c = scb + hh * 8;
                const int idx = srow * 256 + (c ^ ((srow & 7) * 8));
                *(bf16x8*)&ch_[buf][idx] = cvt8(v + hh * 8);
            }
        } else {
#pragma unroll
            for (int hh = 0; hh < 2; ++hh) {
                const int c = scb + hh * 8;
                const int idx = srow * 256 + (c ^ ((srow & 7) * 8));
                *(bf16x8*)&ch_[buf][idx] = *(const bf16x8*)&qu[hh];
            }
        }
    };
    loadc(blockIdx.x);
    storec(0);
    int cur = 0;
    for (int chk = blockIdx.x; chk < nchunks; chk += gridDim.x) {
        const int nxt = chk + gridDim.x;
        if (nxt < nchunks) loadc(nxt);
        __syncthreads();                 // (A) buf[cur] visible; part free
#pragma unroll
        for (int mt = 0; mt < 2; ++mt) {
            f32x4 acc = (f32x4){0.f, 0.f, 0.f, 0.f};
#pragma unroll
            for (int kk = 0; kk < 8; ++kk) {
                const int ai = (mt * 16 + (l & 15)) * 256 + ((kk * 32 + (l >> 4) * 8) ^ ((l & 7) * 8));
                bf16x8 ah = *(const bf16x8*)&ch_[cur][ai];
                acc = __builtin_amdgcn_mfma_f32_16x16x32_bf16(ah, Fh[kk], acc, 0, 0, 0);
                acc = __builtin_amdgcn_mfma_f32_16x16x32_bf16(ah, Fl[kk], acc, 0, 0, 0);
            }
            float p[4];
#pragma unroll
            for (int r = 0; r < 4; ++r) p[r] = fmaxf(acc[r] + b1c, 0.f) * gc;
#pragma unroll
            for (int r = 0; r < 4; ++r) {
                p[r] += __shfl_xor(p[r], 1);
                p[r] += __shfl_xor(p[r], 2);
                p[r] += __shfl_xor(p[r], 4);
                p[r] += __shfl_xor(p[r], 8);
            }
            if ((l & 15) == 0) {
#pragma unroll
                for (int r = 0; r < 4; ++r) part[w][mt * 16 + (l >> 4) * 4 + r] = p[r];
            }
        }
        __syncthreads();                 // (B) part ready; buf[cur] reads done
        if (tid < 32) {
            float s = c0v;
#pragma unroll
            for (int ww = 0; ww < 8; ++ww) s += part[ww][tid];
            out[chk * 32 + tid] = s;
        }
        if (nxt < nchunks) storec(cur ^ 1);
        cur ^= 1;
    }
}

// ---------------- launch ----------------
extern "C" void kernel_launch(void* const* d_in, const int* in_sizes, int n_in,
                              void* d_out, int out_size, void* d_ws, size_t ws_size,
                              hipStream_t stream) {
    const float* data     = (const float*)d_in[0];
    const int*   ei       = (const int*)d_in[1];
    const float* emb      = (const float*)d_in[2];
    const float* lin_w    = (const float*)d_in[3];
    const float* att_i    = (const float*)d_in[4];
    const float* att_j    = (const float*)d_in[5];
    const float* att_em_i = (const float*)d_in[6];
    const float* att_em_j = (const float*)d_in[7];
    const float* gnn_bias = (const float*)d_in[8];
    const float* bn_gamma = (const float*)d_in[9];
    const float* bn_beta  = (const float*)d_in[10];
    // q_w,q_b,k_w,k_b,temperature dead (W=1 -> softmax over single element -> attn==1)
    const float* v_w      = (const float*)d_in[15];
    const float* v_b      = (const float*)d_in[16];
    const float* f_w1     = (const float*)d_in[18];
    const float* f_b1     = (const float*)d_in[19];
    const float* f_w2     = (const float*)d_in[20];
    const float* f_b2     = (const float*)d_in[21];
    const float* out_w    = (const float*)d_in[22];
    const float* out_b    = (const float*)d_in[23];
    float* out = (float*)d_out;

    float* ws = (float*)d_ws;
    float* x      = ws;                                 // BN*D (unused; layout kept)
    float* tmat   = x + (size_t)BN_TOT * D_;            // tb = first BN*64 uints
    float* aggr   = tmat + (size_t)BN_TOT * D_;         // ab = first BN*64 uints
    float* ni     = aggr + (size_t)BN_TOT * D_;         // BN
    float* nj     = ni + BN_TOT;                        // BN
    float* eemi   = nj + BN_TOT;                        // N
    float* eemj   = eemi + N_;                          // N
    float* g      = eemj + N_;                          // D
    float* c0     = g + D_;                             // 1 (pad 8)
    float* scale  = c0 + 8;                             // D
    float* shift  = scale + D_;                         // D
    int* offs     = (int*)(shift + D_);                 // 1024 [zeroed]
    int* cursor   = offs + 1024;                        // 1024 [zeroed]
    float* bn_sum = (float*)(cursor + 1024);            // 128 (unused)
    float* bn_sq  = bn_sum + D_;                        // 128 (unused)
    int* csr_src  = (int*)(bn_sq + D_);                 // E
    float* partials = (float*)(csr_src + E_);           // 16000*256 floats
    float* partial2 = partials + (size_t)16000 * 256;   // 128*256 floats
    __bf16* wcat_h = (__bf16*)(partial2 + 128 * 256);   // 256*128
    __bf16* wcat_l = wcat_h + 256 * 128;                // 256*128
    __bf16* f1_h   = wcat_l + 256 * 128;                // 128*256
    __bf16* f1_l   = f1_h + 128 * 256;                  // 128*256
    unsigned int* xb = (unsigned int*)(f1_l + 128 * 256);  // BN*64 uints
    unsigned int* tb = (unsigned int*)tmat;             // BN*64 uints (packed bf16 t)
    unsigned int* ab = (unsigned int*)aggr;             // BN*64 uints (packed bf16 agg)

    k_prep<<<508, 256, 0, stream>>>(lin_w, v_w, f_w1, emb, att_em_i, att_em_j,
                                    f_w2, f_b2, out_w, out_b,
                                    wcat_h, wcat_l, f1_h, f1_l,
                                    eemi, eemj, g, c0, offs);
    k_count<<<(E_ + 255) / 256, 256, 0, stream>>>(ei, offs);
    k_scan<<<1, 1024, 0, stream>>>(offs);
    k_scatter<<<(E_ + 255) / 256, 256, 0, stream>>>(ei, offs, cursor, csr_src);
    k_mfma_dual<<<500, 512, 0, stream>>>(data, wcat_h, wcat_l, v_b,
                                         att_i, att_j, eemi, eemj,
                                         ni, nj, xb, tb);
    k_sagg<<<BN_TOT / 4, 256, 0, stream>>>(xb, offs, csr_src, ni, nj, gnn_bias, ab, partials);
    k_bn_redA<<<128, 256, 0, stream>>>(partials, partial2);
    k_bn_finB<<<1, 256, 0, stream>>>(partial2, bn_gamma, bn_beta, scale, shift);
    k_mfma_fusion<<<500, 512, 0, stream>>>(ab, tb, f1_h, f1_l, f_b1, scale, shift, g, c0, out);
}